// Round 13
// baseline (1179.072 us; speedup 1.0000x reference)
//
#include <hip/hip_runtime.h>
#include <hip/hip_bf16.h>

#define NNODES 8192
#define NEDGES 262144
#define HDIM 128
#define NLAYERS 6
#define NMASK (NNODES - 1)

typedef __attribute__((ext_vector_type(8))) short bf16x8;   // 8 bf16 = 4 VGPR
typedef __attribute__((ext_vector_type(4))) float f32x4;    // MFMA acc
typedef const __attribute__((address_space(1))) void gvoid;
typedef __attribute__((address_space(3))) void svoid;

__device__ __forceinline__ float silu_f(float x) { return x / (1.0f + __expf(-x)); }
__device__ __forceinline__ unsigned short f2bu(float x) {
    __hip_bfloat16 h = __float2bfloat16(x);
    unsigned short u; __builtin_memcpy(&u, &h, 2); return u;
}
__device__ __forceinline__ float bu2f(unsigned short u) {
    __hip_bfloat16 h; __builtin_memcpy(&h, &u, 2); return __bfloat162float(h);
}

// load a bf16x8 A-frag from 8B-aligned LDS (stride-132 rows) as two b64s
__device__ __forceinline__ bf16x8 ld_a8(const unsigned short* p) {
    uint2 lo = *(const uint2*)p;
    uint2 hi = *(const uint2*)(p + 4);
    bf16x8 a;
    ((uint2*)&a)[0] = lo;
    ((uint2*)&a)[1] = hi;
    return a;
}

// cooperative stage of one contiguous 8KB slice (4096 shorts) into LDS.
__device__ __forceinline__ void stage_slice(const unsigned short* src,
                                            unsigned short* dst, int w) {
    const unsigned short* s = src + w * 1024;
    unsigned short* d = dst + w * 1024;
    __builtin_amdgcn_global_load_lds((gvoid*)s, (svoid*)d, 16, 0, 0);
    __builtin_amdgcn_global_load_lds((gvoid*)(s + 512), (svoid*)(d + 512), 16, 0, 0);
}

// ---------------------------------------------------------------- probes
__global__ void detect_kernel(const int* __restrict__ ei32, int* __restrict__ flags) {
    if (blockIdx.x == 0 && threadIdx.x == 0) {
        flags[1] = (ei32[1] == 0 && ei32[3] == 0 && ei32[5] == 0 && ei32[7] == 0) ? 1 : 0;
    }
}
__device__ __forceinline__ int load_idx(const void* ei, int is64, int i) {
    int v = is64 ? (int)(((const long long*)ei)[i]) : ((const int*)ei)[i];
    return v & NMASK;
}

// ---------------------------------------------------------------- pos init
__global__ void pos_init_kernel(const float* __restrict__ pin, float* __restrict__ pos) {
    int i = blockIdx.x * blockDim.x + threadIdx.x;
    if (i < NNODES * 3) pos[i] = pin[i];
}

// ---------------------------------------------------------------- edge sort (counting sort by row)
__global__ void cnt_kernel(const void* __restrict__ ei, const int* __restrict__ flags,
                           int* __restrict__ cnt) {
    int i = blockIdx.x * blockDim.x + threadIdx.x;
    if (i < NEDGES) atomicAdd(&cnt[load_idx(ei, flags[1], i)], 1);
}
__global__ void scan_kernel(const int* __restrict__ cnt, int* __restrict__ woff,
                            float* __restrict__ deg) {
    __shared__ int sums[256];
    const int t = threadIdx.x;
    const int base = t * 32;
    int s = 0;
#pragma unroll
    for (int i = 0; i < 32; ++i) s += cnt[base + i];
    sums[t] = s;
    __syncthreads();
    if (t == 0) {
        int run = 0;
        for (int k = 0; k < 256; ++k) { int v = sums[k]; sums[k] = run; run += v; }
    }
    __syncthreads();
    int run = sums[t];
#pragma unroll
    for (int i = 0; i < 32; ++i) {
        int c = cnt[base + i];
        woff[base + i] = run;
        deg[base + i] = (float)c;
        run += c;
    }
}
__global__ void scatter_kernel(const void* __restrict__ ei, const int* __restrict__ flags,
                               int* __restrict__ woff,
                               int* __restrict__ rowS, int* __restrict__ colS) {
    int i = blockIdx.x * blockDim.x + threadIdx.x;
    if (i < NEDGES) {
        const int is64 = flags[1];
        int r = load_idx(ei, is64, i);
        int c = load_idx(ei, is64, NEDGES + i);
        int p = atomicAdd(&woff[r], 1);
        rowS[p] = r;
        colS[p] = c;
    }
}

// ---------------------------------------------------------------- weight prep
// Blocked layout [slice][chunk][128 n][8 k] (k = slice*32 + chunk*8 + j).
__global__ void prep_weights_kernel(const float* __restrict__ eW1,
                                    const float* __restrict__ eW2,
                                    const float* __restrict__ cW1,
                                    const float* __restrict__ nW1,
                                    const float* __restrict__ nW2,
                                    unsigned short* __restrict__ w1tb,
                                    unsigned short* __restrict__ w2tb,
                                    unsigned short* __restrict__ c1tb,
                                    unsigned short* __restrict__ n1tb,
                                    unsigned short* __restrict__ n2tb,
                                    float* __restrict__ w1d) {
    const int TB = NLAYERS * 8 * 4 * 128 * 8;   // 196608
    const int TS = NLAYERS * 4 * 4 * 128 * 8;   // 98304
    const int TD = NLAYERS * 128;
    const int TOT = 2 * TB + 3 * TS + TD;
    for (int i = blockIdx.x * blockDim.x + threadIdx.x; i < TOT;
         i += gridDim.x * blockDim.x) {
        if (i < TB) {
            int j = i & 7, r = i >> 3;
            int n = r & 127; r >>= 7;
            int ch = r & 3; r >>= 2;
            int sl = r & 7; int l = r >> 3;
            int k = sl * 32 + ch * 8 + j;
            w1tb[i] = f2bu(eW1[((size_t)l * 257 + k) * 128 + n]);
        } else if (i < TB + TS) {
            int q = i - TB;
            int j = q & 7, r = q >> 3;
            int n = r & 127; r >>= 7;
            int ch = r & 3; r >>= 2;
            int sl = r & 3; int l = r >> 2;
            int k = sl * 32 + ch * 8 + j;
            w2tb[q] = f2bu(eW2[((size_t)l * 128 + k) * 128 + n]);
        } else if (i < TB + 2 * TS) {
            int q = i - TB - TS;
            int j = q & 7, r = q >> 3;
            int n = r & 127; r >>= 7;
            int ch = r & 3; r >>= 2;
            int sl = r & 3; int l = r >> 2;
            int k = sl * 32 + ch * 8 + j;
            c1tb[q] = f2bu(cW1[((size_t)l * 128 + k) * 128 + n]);
        } else if (i < 2 * TB + 2 * TS) {
            int q = i - TB - 2 * TS;
            int j = q & 7, r = q >> 3;
            int n = r & 127; r >>= 7;
            int ch = r & 3; r >>= 2;
            int sl = r & 7; int l = r >> 3;
            int k = sl * 32 + ch * 8 + j;
            n1tb[q] = f2bu(nW1[((size_t)l * 256 + k) * 128 + n]);
        } else if (i < 2 * TB + 3 * TS) {
            int q = i - 2 * TB - 2 * TS;
            int j = q & 7, r = q >> 3;
            int n = r & 127; r >>= 7;
            int ch = r & 3; r >>= 2;
            int sl = r & 3; int l = r >> 2;
            int k = sl * 32 + ch * 8 + j;
            n2tb[q] = f2bu(nW2[((size_t)l * 128 + k) * 128 + n]);
        } else {
            int r = i - 2 * TB - 3 * TS, l = r / 128, n = r % 128;
            w1d[r] = eW1[((size_t)l * 257 + 256) * 128 + n];
        }
    }
}

// ---------------------------------------------------------------- injection MLP (bf16 h out)
__global__ __launch_bounds__(256) void inj_kernel(
    const float* __restrict__ atom, const float* __restrict__ z,
    const float* __restrict__ W1, const float* __restrict__ b1,
    const float* __restrict__ W2, const float* __restrict__ b2,
    const float* __restrict__ W3, const float* __restrict__ b3,
    unsigned short* __restrict__ hb)
{
    __shared__ __align__(16) float in_s[16][84];
    __shared__ __align__(16) float s1[16][260];
    __shared__ __align__(16) float s2[16][132];
    const int tid = threadIdx.x;
    const int n0 = blockIdx.x * 16;

    if (tid < 80) {
        for (int e = 0; e < 16; ++e) {
            int n = n0 + e;
            in_s[e][tid] = (tid < 16) ? atom[n * 16 + tid] : z[(n >> 5) * 64 + (tid - 16)];
        }
    }
    __syncthreads();
    {
        float acc[16];
        float bias = b1[tid];
#pragma unroll
        for (int e = 0; e < 16; ++e) acc[e] = bias;
        for (int k4 = 0; k4 < 20; ++k4) {
            float w0 = W1[(k4 * 4 + 0) * 256 + tid];
            float w1 = W1[(k4 * 4 + 1) * 256 + tid];
            float w2 = W1[(k4 * 4 + 2) * 256 + tid];
            float w3 = W1[(k4 * 4 + 3) * 256 + tid];
#pragma unroll
            for (int e = 0; e < 16; ++e) {
                const float4 v = *(const float4*)&in_s[e][k4 * 4];
                acc[e] += v.x * w0 + v.y * w1 + v.z * w2 + v.w * w3;
            }
        }
#pragma unroll
        for (int e = 0; e < 16; ++e) s1[e][tid] = silu_f(acc[e]);
    }
    __syncthreads();
    const int j = tid & 127, hv = tid >> 7;
    {
        float acc[8];
        float bias = b2[j];
#pragma unroll
        for (int e = 0; e < 8; ++e) acc[e] = bias;
        for (int k4 = 0; k4 < 64; ++k4) {
            float w0 = W2[(k4 * 4 + 0) * 128 + j];
            float w1 = W2[(k4 * 4 + 1) * 128 + j];
            float w2 = W2[(k4 * 4 + 2) * 128 + j];
            float w3 = W2[(k4 * 4 + 3) * 128 + j];
#pragma unroll
            for (int e = 0; e < 8; ++e) {
                const float4 v = *(const float4*)&s1[hv * 8 + e][k4 * 4];
                acc[e] += v.x * w0 + v.y * w1 + v.z * w2 + v.w * w3;
            }
        }
#pragma unroll
        for (int e = 0; e < 8; ++e) s2[hv * 8 + e][j] = silu_f(acc[e]);
    }
    __syncthreads();
    {
        float acc[8];
        float bias = b3[j];
#pragma unroll
        for (int e = 0; e < 8; ++e) acc[e] = bias;
        for (int k4 = 0; k4 < 32; ++k4) {
            float w0 = W3[(k4 * 4 + 0) * 128 + j];
            float w1 = W3[(k4 * 4 + 1) * 128 + j];
            float w2 = W3[(k4 * 4 + 2) * 128 + j];
            float w3 = W3[(k4 * 4 + 3) * 128 + j];
#pragma unroll
            for (int e = 0; e < 8; ++e) {
                const float4 v = *(const float4*)&s2[hv * 8 + e][k4 * 4];
                acc[e] += v.x * w0 + v.y * w1 + v.z * w2 + v.w * w3;
            }
        }
#pragma unroll
        for (int e = 0; e < 8; ++e)
            hb[(size_t)(n0 + hv * 8 + e) * HDIM + j] = f2bu(acc[e]);
    }
}

// ---------------------------------------------------------------- MFMA edge kernel
// 128 sorted edges x 128 ch, 4 waves, fully wave-local except Bbuf staging.
// Cbuf stride 132 shorts (264 B): 2-bank shift/row; A-frags via 2x b64 (8B
// aligned). Meta in pad cols: dsq f32 @128 (later cw), row @130, col @131.
// dp kept in registers of the owning wave. LDS = 33792 + 8192 = 41984 B.
// MFMA layouts (HW-verified 16x16x32 bf16): A[m=l16][k=quad*8+j],
// B[k=quad*8+j][n=l16], D[m=quad*4+r][n=l16].
__global__ __launch_bounds__(256, 3) void edge_mfma_kernel(
    const unsigned short* __restrict__ hb, const float* __restrict__ pos,
    const int* __restrict__ rowS, const int* __restrict__ colS,
    const unsigned short* __restrict__ w1tb,   // [8 slice][4096]
    const unsigned short* __restrict__ w2tb,   // [4 slice][4096]
    const unsigned short* __restrict__ c1tb,   // [4 slice][4096]
    const float* __restrict__ w1d,
    const float* __restrict__ eb1, const float* __restrict__ eb2,
    const float* __restrict__ cb1, const float* __restrict__ cw2,
    float* __restrict__ agg, float* __restrict__ cu)
{
    __shared__ __align__(16) unsigned short Cbuf[128][132];  // h1/m + meta pad
    __shared__ __align__(16) unsigned short Bbuf[4096];      // one staged slice

    const int tid = threadIdx.x;
    const int e0 = blockIdx.x * 128;
    const int L = tid & 63, w = tid >> 6;
    const int quad = L >> 4, l16 = L & 15;
    const int m0 = w * 32;

    stage_slice(w1tb, Bbuf, w);   // slice 0 in flight during setup

    // per-wave setup: wave w owns edges/rows [m0, m0+32)
    float dx = 0.f, dy = 0.f, dz = 0.f;
    if (L < 32) {
        const int eg = e0 + m0 + L;
        int r = rowS[eg], c = colS[eg];
        dx = pos[r * 3 + 0] - pos[c * 3 + 0];
        dy = pos[r * 3 + 1] - pos[c * 3 + 1];
        dz = pos[r * 3 + 2] - pos[c * 3 + 2];
        *(float*)&Cbuf[m0 + L][128] = dx * dx + dy * dy + dz * dz;  // dsq
        Cbuf[m0 + L][130] = (unsigned short)r;
        Cbuf[m0 + L][131] = (unsigned short)c;
    }
    // own-wave meta reads (in-order DS, no barrier needed)
    const int r0 = Cbuf[m0 + l16][130];
    const int r1 = Cbuf[m0 + 16 + l16][130];
    const int c0 = Cbuf[m0 + l16][131];
    const int c1 = Cbuf[m0 + 16 + l16][131];
    __syncthreads();   // Bbuf slice 0 staged

    f32x4 acc[2][8];
    const f32x4 zero = {0.f, 0.f, 0.f, 0.f};

    // ---------- GEMM1: ef[128 x 256] @ W1, 8 k-slices (single-buffered)
#pragma unroll
    for (int mt = 0; mt < 2; ++mt)
#pragma unroll
        for (int nt = 0; nt < 8; ++nt) acc[mt][nt] = zero;

#pragma unroll
    for (int kc = 0; kc < 8; ++kc) {
        const int kk = (kc & 3) * 32 + quad * 8;
        const int n0i = (kc < 4) ? r0 : c0;
        const int n1i = (kc < 4) ? r1 : c1;
        bf16x8 a0 = *(const bf16x8*)(hb + (size_t)n0i * HDIM + kk);
        bf16x8 a1 = *(const bf16x8*)(hb + (size_t)n1i * HDIM + kk);
        const unsigned short* bp = Bbuf + quad * 1024;
#pragma unroll
        for (int nt = 0; nt < 8; ++nt) {
            bf16x8 b = *(const bf16x8*)&bp[(nt * 16 + l16) * 8];
            acc[0][nt] = __builtin_amdgcn_mfma_f32_16x16x32_bf16(a0, b, acc[0][nt], 0, 0, 0);
            acc[1][nt] = __builtin_amdgcn_mfma_f32_16x16x32_bf16(a1, b, acc[1][nt], 0, 0, 0);
        }
        __syncthreads();   // slice reads done
        stage_slice((kc < 7) ? w1tb + (kc + 1) * 4096 : w2tb, Bbuf, w);
        if (kc == 7) {
            // epilogue1 overlaps w2-slice0 staging (own rows only)
#pragma unroll
            for (int nt = 0; nt < 8; ++nt) {
                const int n = nt * 16 + l16;
                const float wd = w1d[n];
                const float bias = eb1[n];
#pragma unroll
                for (int mt = 0; mt < 2; ++mt)
#pragma unroll
                    for (int r = 0; r < 4; ++r) {
                        const int m = m0 + mt * 16 + quad * 4 + r;
                        float dsq = *(const float*)&Cbuf[m][128];
                        Cbuf[m][n] = f2bu(silu_f(acc[mt][nt][r] + bias + dsq * wd));
                    }
            }
        }
        __syncthreads();   // next slice staged
    }

    // ---------- GEMM2: h1 @ W2 -> m (A = own-wave Cbuf rows, in-order DS)
#pragma unroll
    for (int mt = 0; mt < 2; ++mt)
#pragma unroll
        for (int nt = 0; nt < 8; ++nt) acc[mt][nt] = zero;
#pragma unroll
    for (int kc = 0; kc < 4; ++kc) {
        const int kk = kc * 32 + quad * 8;
        bf16x8 a0 = ld_a8(&Cbuf[m0 + l16][kk]);
        bf16x8 a1 = ld_a8(&Cbuf[m0 + 16 + l16][kk]);
        const unsigned short* bp = Bbuf + quad * 1024;
#pragma unroll
        for (int nt = 0; nt < 8; ++nt) {
            bf16x8 b = *(const bf16x8*)&bp[(nt * 16 + l16) * 8];
            acc[0][nt] = __builtin_amdgcn_mfma_f32_16x16x32_bf16(a0, b, acc[0][nt], 0, 0, 0);
            acc[1][nt] = __builtin_amdgcn_mfma_f32_16x16x32_bf16(a1, b, acc[1][nt], 0, 0, 0);
        }
        __syncthreads();
        stage_slice((kc < 3) ? w2tb + (kc + 1) * 4096 : c1tb, Bbuf, w);
        if (kc == 3) {
            // epilogue2: m = silu(acc + eb2) -> own rows
#pragma unroll
            for (int nt = 0; nt < 8; ++nt) {
                const int n = nt * 16 + l16;
                const float bias = eb2[n];
#pragma unroll
                for (int mt = 0; mt < 2; ++mt)
#pragma unroll
                    for (int r = 0; r < 4; ++r) {
                        const int m = m0 + mt * 16 + quad * 4 + r;
                        Cbuf[m][n] = f2bu(silu_f(acc[mt][nt][r] + bias));
                    }
            }
        }
        __syncthreads();
    }

    // ---------- GEMM3: m @ cW1 ; cw = silu(c1+cb1) . cW2
#pragma unroll
    for (int mt = 0; mt < 2; ++mt)
#pragma unroll
        for (int nt = 0; nt < 8; ++nt) acc[mt][nt] = zero;
#pragma unroll
    for (int kc = 0; kc < 4; ++kc) {
        const int kk = kc * 32 + quad * 8;
        bf16x8 a0 = ld_a8(&Cbuf[m0 + l16][kk]);
        bf16x8 a1 = ld_a8(&Cbuf[m0 + 16 + l16][kk]);
        const unsigned short* bp = Bbuf + quad * 1024;
#pragma unroll
        for (int nt = 0; nt < 8; ++nt) {
            bf16x8 b = *(const bf16x8*)&bp[(nt * 16 + l16) * 8];
            acc[0][nt] = __builtin_amdgcn_mfma_f32_16x16x32_bf16(a0, b, acc[0][nt], 0, 0, 0);
            acc[1][nt] = __builtin_amdgcn_mfma_f32_16x16x32_bf16(a1, b, acc[1][nt], 0, 0, 0);
        }
        if (kc < 3) {
            __syncthreads();
            stage_slice(c1tb + (kc + 1) * 4096, Bbuf, w);
            __syncthreads();
        }
    }
    {
        float s[2][4] = {{0.f, 0.f, 0.f, 0.f}, {0.f, 0.f, 0.f, 0.f}};
#pragma unroll
        for (int nt = 0; nt < 8; ++nt) {
            const int n = nt * 16 + l16;
            const float bias = cb1[n];
            const float wv = cw2[n];
#pragma unroll
            for (int mt = 0; mt < 2; ++mt)
#pragma unroll
                for (int r = 0; r < 4; ++r)
                    s[mt][r] += silu_f(acc[mt][nt][r] + bias) * wv;
        }
#pragma unroll
        for (int mt = 0; mt < 2; ++mt)
#pragma unroll
            for (int r = 0; r < 4; ++r) {
                float v = s[mt][r];
                v += __shfl_xor(v, 1);
                v += __shfl_xor(v, 2);
                v += __shfl_xor(v, 4);
                v += __shfl_xor(v, 8);
                if (l16 == 0)
                    *(float*)&Cbuf[m0 + mt * 16 + quad * 4 + r][128] = v;  // cw
            }
    }
    // NO final barrier: scatters below are wave-local (own rows only)

    // ---------- coord scatter: per-edge atomics with register dp
    if (L < 32) {
        const int m = m0 + L;
        const float cwv = *(const float*)&Cbuf[m][128];
        const int r = Cbuf[m][130];
        atomicAdd(&cu[r * 3 + 0], cwv * dx);
        atomicAdd(&cu[r * 3 + 1], cwv * dy);
        atomicAdd(&cu[r * 3 + 2], cwv * dz);
    }
    // ---------- agg scatter: paired-channel segmented run-accumulate (own rows)
    {
        const int p = L;   // 0..63 -> channels 2p, 2p+1
        int curr = Cbuf[m0][130];
        float s0 = 0.0f, s1 = 0.0f;
#pragma unroll 4
        for (int i = 0; i < 32; ++i) {
            const int e = m0 + i;
            int r = Cbuf[e][130];
            if (r != curr) {
                atomicAdd(&agg[(size_t)curr * HDIM + 2 * p], s0);
                atomicAdd(&agg[(size_t)curr * HDIM + 2 * p + 1], s1);
                s0 = 0.0f; s1 = 0.0f; curr = r;
            }
            unsigned int v = *(const unsigned int*)&Cbuf[e][2 * p];
            s0 += bu2f((unsigned short)(v & 0xffffu));
            s1 += bu2f((unsigned short)(v >> 16));
        }
        atomicAdd(&agg[(size_t)curr * HDIM + 2 * p], s0);
        atomicAdd(&agg[(size_t)curr * HDIM + 2 * p + 1], s1);
    }
}

// ---------------------------------------------------------------- MFMA node kernel
// 32 nodes x 128 ch per block, 2 waves, 128 threads, grid 256. Zero barriers.
// Also ZEROES agg/cu after consuming them (replaces per-layer memsets).
__global__ __launch_bounds__(128) void node_mfma_kernel(
    const unsigned short* __restrict__ hb,
    float* __restrict__ agg,
    float* __restrict__ cu, const float* __restrict__ deg,
    const unsigned short* __restrict__ n1tb,   // [8 slice][4096]
    const unsigned short* __restrict__ n2tb,   // [4 slice][4096]
    const float* __restrict__ b1, const float* __restrict__ b2,
    const float* __restrict__ lg, const float* __restrict__ lb,
    unsigned short* __restrict__ h2b,
    float* __restrict__ pos)
{
    __shared__ __align__(16) unsigned short Cbuf[32][136];
    const int tid = threadIdx.x;
    const int n0 = blockIdx.x * 32;

    if (tid < 32) {
        int n = n0 + tid;
        float inv = 1.0f / (deg[n] + 1e-6f);
        pos[n * 3 + 0] += cu[n * 3 + 0] * inv;
        pos[n * 3 + 1] += cu[n * 3 + 1] * inv;
        pos[n * 3 + 2] += cu[n * 3 + 2] * inv;
        cu[n * 3 + 0] = 0.0f;   // zero for next layer's edge kernel
        cu[n * 3 + 1] = 0.0f;
        cu[n * 3 + 2] = 0.0f;
    }

    const int L = tid & 63, w = tid >> 6;     // w in {0,1}
    const int quad = L >> 4, l16 = L & 15;
    const int m0 = w * 16;
    const int row = n0 + m0 + l16;

    f32x4 acc[8];
    const f32x4 zero = {0.f, 0.f, 0.f, 0.f};

    // ---------- GEMM1: [h | agg] @ nW1
#pragma unroll
    for (int nt = 0; nt < 8; ++nt) acc[nt] = zero;
#pragma unroll
    for (int kc = 0; kc < 8; ++kc) {
        bf16x8 a;
        if (kc < 4) {
            const int kk = kc * 32 + quad * 8;
            a = *(const bf16x8*)(hb + (size_t)row * HDIM + kk);
        } else {
            const int kk = (kc - 4) * 32 + quad * 8;
            const float4* p = (const float4*)(agg + (size_t)row * HDIM + kk);
            float4 u0 = p[0], u1 = p[1];
            a[0] = (short)f2bu(u0.x); a[1] = (short)f2bu(u0.y);
            a[2] = (short)f2bu(u0.z); a[3] = (short)f2bu(u0.w);
            a[4] = (short)f2bu(u1.x); a[5] = (short)f2bu(u1.y);
            a[6] = (short)f2bu(u1.z); a[7] = (short)f2bu(u1.w);
        }
        const unsigned short* bp = n1tb + ((kc * 4 + quad) * 128) * 8;
#pragma unroll
        for (int nt = 0; nt < 8; ++nt) {
            bf16x8 b = *(const bf16x8*)(bp + (nt * 16 + l16) * 8);
            acc[nt] = __builtin_amdgcn_mfma_f32_16x16x32_bf16(a, b, acc[nt], 0, 0, 0);
        }
    }
    // zero own agg rows (loads above already consumed): lane (quad,l16) zeroes
    // row n0+m0+l16, floats [quad*32, quad*32+32)
    {
        const float4 z4 = {0.f, 0.f, 0.f, 0.f};
        float4* ap = (float4*)(agg + (size_t)row * HDIM + quad * 32);
#pragma unroll
        for (int i = 0; i < 8; ++i) ap[i] = z4;
    }
#pragma unroll
    for (int nt = 0; nt < 8; ++nt) {
        const int n = nt * 16 + l16;
        const float bias = b1[n];
#pragma unroll
        for (int r = 0; r < 4; ++r) {
            const int m = m0 + quad * 4 + r;
            Cbuf[m][n] = f2bu(silu_f(acc[nt][r] + bias));
        }
    }

    // ---------- GEMM2: s1 @ nW2 -> nu
#pragma unroll
    for (int nt = 0; nt < 8; ++nt) acc[nt] = zero;
#pragma unroll
    for (int kc = 0; kc < 4; ++kc) {
        const int kk = kc * 32 + quad * 8;
        bf16x8 a = *(const bf16x8*)&Cbuf[m0 + l16][kk];
        const unsigned short* bp = n2tb + ((kc * 4 + quad) * 128) * 8;
#pragma unroll
        for (int nt = 0; nt < 8; ++nt) {
            bf16x8 b = *(const bf16x8*)(bp + (nt * 16 + l16) * 8);
            acc[nt] = __builtin_amdgcn_mfma_f32_16x16x32_bf16(a, b, acc[nt], 0, 0, 0);
        }
    }

    // epilogue 2: x = h + nu + b2 ; LN via 16-lane shuffle ; write h2b
#pragma unroll
    for (int nt = 0; nt < 8; ++nt) {
        const int n = nt * 16 + l16;
        const float bias = b2[n];
#pragma unroll
        for (int r = 0; r < 4; ++r) {
            const int m = m0 + quad * 4 + r;
            acc[nt][r] += bias + bu2f(hb[(size_t)(n0 + m) * HDIM + n]);
        }
    }
    float mu[4], rs[4];
#pragma unroll
    for (int r = 0; r < 4; ++r) {
        float s = 0.0f, ss = 0.0f;
#pragma unroll
        for (int nt = 0; nt < 8; ++nt) {
            float x = acc[nt][r];
            s += x; ss += x * x;
        }
#pragma unroll
        for (int d = 1; d < 16; d <<= 1) {
            s += __shfl_xor(s, d);
            ss += __shfl_xor(ss, d);
        }
        float m_ = s * (1.0f / 128.0f);
        float var = ss * (1.0f / 128.0f) - m_ * m_;
        mu[r] = m_;
        rs[r] = rsqrtf(fmaxf(var, 0.0f) + 1e-5f);
    }
#pragma unroll
    for (int nt = 0; nt < 8; ++nt) {
        const int n = nt * 16 + l16;
        const float gg = lg[n], bb = lb[n];
#pragma unroll
        for (int r = 0; r < 4; ++r) {
            const int m = m0 + quad * 4 + r;
            float val = (acc[nt][r] - mu[r]) * rs[r] * gg + bb;
            h2b[(size_t)(n0 + m) * HDIM + n] = f2bu(val);
        }
    }
}

// ---------------------------------------------------------------- launch
extern "C" void kernel_launch(void* const* d_in, const int* in_sizes, int n_in,
                              void* d_out, int out_size, void* d_ws, size_t ws_size,
                              hipStream_t stream) {
    const float* zF    = (const float*)d_in[0];
    const float* atomF = (const float*)d_in[1];
    const float* posI  = (const float*)d_in[2];
    const void*  ei    = d_in[3];
    const float* iW1 = (const float*)d_in[5];  const float* ib1 = (const float*)d_in[6];
    const float* iW2 = (const float*)d_in[7];  const float* ib2 = (const float*)d_in[8];
    const float* iW3 = (const float*)d_in[9];  const float* ib3 = (const float*)d_in[10];
    const float* eW1 = (const float*)d_in[11]; const float* eb1 = (const float*)d_in[12];
    const float* eW2 = (const float*)d_in[13]; const float* eb2 = (const float*)d_in[14];
    const float* nW1 = (const float*)d_in[15]; const float* nb1 = (const float*)d_in[16];
    const float* nW2 = (const float*)d_in[17]; const float* nb2 = (const float*)d_in[18];
    const float* cW1 = (const float*)d_in[19]; const float* cb1 = (const float*)d_in[20];
    const float* cW2 = (const float*)d_in[21];
    const float* lng = (const float*)d_in[22]; const float* lnb = (const float*)d_in[23];

    float* pos = (float*)d_out;   // fp32 output (verified R5)

    float* ws = (float*)d_ws;
    int* flags = (int*)d_ws;
    size_t cur = 16;
    auto carve = [&](size_t n) { float* p = ws + cur; cur += n; return p; };
    float* deg  = carve(NNODES);
    float* cu   = carve((size_t)NNODES * 3);
    float* agg  = carve((size_t)NNODES * HDIM);
    unsigned short* hbA = (unsigned short*)carve((size_t)NNODES * HDIM / 2);
    unsigned short* hbB = (unsigned short*)carve((size_t)NNODES * HDIM / 2);
    unsigned short* w1tb = (unsigned short*)carve((size_t)NLAYERS * 8 * 4096 / 2);
    unsigned short* w2tb = (unsigned short*)carve((size_t)NLAYERS * 4 * 4096 / 2);
    unsigned short* c1tb = (unsigned short*)carve((size_t)NLAYERS * 4 * 4096 / 2);
    unsigned short* n1tb = (unsigned short*)carve((size_t)NLAYERS * 8 * 4096 / 2);
    unsigned short* n2tb = (unsigned short*)carve((size_t)NLAYERS * 4 * 4096 / 2);
    float* w1d  = carve(NLAYERS * 128);
    int* cnt    = (int*)carve(NNODES);
    int* woff   = (int*)carve(NNODES);
    int* rowS   = (int*)carve(NEDGES);
    int* colS   = (int*)carve(NEDGES);

    detect_kernel<<<1, 64, 0, stream>>>((const int*)ei, flags);
    pos_init_kernel<<<(NNODES * 3 + 255) / 256, 256, 0, stream>>>(posI, pos);

    hipMemsetAsync(cnt, 0, NNODES * sizeof(int), stream);
    cnt_kernel<<<NEDGES / 256, 256, 0, stream>>>(ei, flags, cnt);
    scan_kernel<<<1, 256, 0, stream>>>(cnt, woff, deg);
    scatter_kernel<<<NEDGES / 256, 256, 0, stream>>>(ei, flags, woff, rowS, colS);

    prep_weights_kernel<<<2691, 256, 0, stream>>>(eW1, eW2, cW1, nW1, nW2,
                                                  w1tb, w2tb, c1tb, n1tb, n2tb, w1d);
    inj_kernel<<<NNODES / 16, 256, 0, stream>>>(atomF, zF, iW1, ib1, iW2, ib2, iW3, ib3,
                                                hbA);

    // layer-0 zeroing only; node_mfma_kernel zeroes agg/cu for later layers
    hipMemsetAsync(agg, 0, (size_t)NNODES * HDIM * sizeof(float), stream);
    hipMemsetAsync(cu, 0, (size_t)NNODES * 3 * sizeof(float), stream);

    unsigned short* hb = hbA;
    unsigned short* ob = hbB;
    for (int l = 0; l < NLAYERS; ++l) {
        edge_mfma_kernel<<<NEDGES / 128, 256, 0, stream>>>(
            hb, pos, rowS, colS,
            w1tb + (size_t)l * 8 * 4096,
            w2tb + (size_t)l * 4 * 4096,
            c1tb + (size_t)l * 4 * 4096,
            w1d + (size_t)l * 128,
            eb1 + l * 128, eb2 + l * 128, cb1 + l * 128, cW2 + l * 128,
            agg, cu);
        node_mfma_kernel<<<NNODES / 32, 128, 0, stream>>>(
            hb, agg, cu, deg,
            n1tb + (size_t)l * 8 * 4096,
            n2tb + (size_t)l * 4 * 4096,
            nb1 + l * 128, nb2 + l * 128,
            lng + l * 128, lnb + l * 128,
            /*h2b=*/ob, pos);
        unsigned short* tb = hb; hb = ob; ob = tb;
    }
}

// Round 14
// 776.922 us; speedup vs baseline: 1.5176x; 1.5176x over previous
//
#include <hip/hip_runtime.h>
#include <hip/hip_bf16.h>

#define NNODES 8192
#define NEDGES 262144
#define HDIM 128
#define NLAYERS 6
#define NMASK (NNODES - 1)

typedef __attribute__((ext_vector_type(8))) short bf16x8;   // 8 bf16 = 4 VGPR
typedef __attribute__((ext_vector_type(4))) float f32x4;    // MFMA acc
typedef const __attribute__((address_space(1))) void gvoid;
typedef __attribute__((address_space(3))) void svoid;

// fast silu: v_rcp instead of precise-div sequence (~1 ulp rcp, fine at bf16 out)
__device__ __forceinline__ float silu_f(float x) {
    return x * __builtin_amdgcn_rcpf(1.0f + __expf(-x));
}
// fast fp32->bf16: round-half-away via +0x8000 (2 VALU ops; inputs finite)
__device__ __forceinline__ unsigned short f2bu(float x) {
    unsigned int u; __builtin_memcpy(&u, &x, 4);
    return (unsigned short)((u + 0x8000u) >> 16);
}
__device__ __forceinline__ float bu2f(unsigned short u) {
    unsigned int v = ((unsigned int)u) << 16;
    float f; __builtin_memcpy(&f, &v, 4);
    return f;
}

// cooperative stage of one contiguous 8KB slice (4096 shorts) into LDS.
__device__ __forceinline__ void stage_slice(const unsigned short* src,
                                            unsigned short* dst, int w) {
    const unsigned short* s = src + w * 1024;
    unsigned short* d = dst + w * 1024;
    __builtin_amdgcn_global_load_lds((gvoid*)s, (svoid*)d, 16, 0, 0);
    __builtin_amdgcn_global_load_lds((gvoid*)(s + 512), (svoid*)(d + 512), 16, 0, 0);
}

// ---------------------------------------------------------------- probes
__global__ void detect_kernel(const int* __restrict__ ei32, int* __restrict__ flags) {
    if (blockIdx.x == 0 && threadIdx.x == 0) {
        flags[1] = (ei32[1] == 0 && ei32[3] == 0 && ei32[5] == 0 && ei32[7] == 0) ? 1 : 0;
    }
}
__device__ __forceinline__ int load_idx(const void* ei, int is64, int i) {
    int v = is64 ? (int)(((const long long*)ei)[i]) : ((const int*)ei)[i];
    return v & NMASK;
}

// ---------------------------------------------------------------- pos init
__global__ void pos_init_kernel(const float* __restrict__ pin, float* __restrict__ pos) {
    int i = blockIdx.x * blockDim.x + threadIdx.x;
    if (i < NNODES * 3) pos[i] = pin[i];
}

// ---------------------------------------------------------------- edge sort (counting sort by row)
__global__ void cnt_kernel(const void* __restrict__ ei, const int* __restrict__ flags,
                           int* __restrict__ cnt) {
    int i = blockIdx.x * blockDim.x + threadIdx.x;
    if (i < NEDGES) atomicAdd(&cnt[load_idx(ei, flags[1], i)], 1);
}
__global__ void scan_kernel(const int* __restrict__ cnt, int* __restrict__ woff,
                            float* __restrict__ deg) {
    __shared__ int sums[256];
    const int t = threadIdx.x;
    const int base = t * 32;
    int s = 0;
#pragma unroll
    for (int i = 0; i < 32; ++i) s += cnt[base + i];
    sums[t] = s;
    __syncthreads();
    if (t == 0) {
        int run = 0;
        for (int k = 0; k < 256; ++k) { int v = sums[k]; sums[k] = run; run += v; }
    }
    __syncthreads();
    int run = sums[t];
#pragma unroll
    for (int i = 0; i < 32; ++i) {
        int c = cnt[base + i];
        woff[base + i] = run;
        deg[base + i] = (float)c;
        run += c;
    }
}
__global__ void scatter_kernel(const void* __restrict__ ei, const int* __restrict__ flags,
                               int* __restrict__ woff,
                               int* __restrict__ rowS, int* __restrict__ colS) {
    int i = blockIdx.x * blockDim.x + threadIdx.x;
    if (i < NEDGES) {
        const int is64 = flags[1];
        int r = load_idx(ei, is64, i);
        int c = load_idx(ei, is64, NEDGES + i);
        int p = atomicAdd(&woff[r], 1);
        rowS[p] = r;
        colS[p] = c;
    }
}

// ---------------------------------------------------------------- weight prep
// Blocked layout [slice][chunk][128 n][8 k] (k = slice*32 + chunk*8 + j).
__global__ void prep_weights_kernel(const float* __restrict__ eW1,
                                    const float* __restrict__ eW2,
                                    const float* __restrict__ cW1,
                                    const float* __restrict__ nW1,
                                    const float* __restrict__ nW2,
                                    unsigned short* __restrict__ w1tb,
                                    unsigned short* __restrict__ w2tb,
                                    unsigned short* __restrict__ c1tb,
                                    unsigned short* __restrict__ n1tb,
                                    unsigned short* __restrict__ n2tb,
                                    float* __restrict__ w1d) {
    const int TB = NLAYERS * 8 * 4 * 128 * 8;   // 196608
    const int TS = NLAYERS * 4 * 4 * 128 * 8;   // 98304
    const int TD = NLAYERS * 128;
    const int TOT = 2 * TB + 3 * TS + TD;
    for (int i = blockIdx.x * blockDim.x + threadIdx.x; i < TOT;
         i += gridDim.x * blockDim.x) {
        if (i < TB) {
            int j = i & 7, r = i >> 3;
            int n = r & 127; r >>= 7;
            int ch = r & 3; r >>= 2;
            int sl = r & 7; int l = r >> 3;
            int k = sl * 32 + ch * 8 + j;
            w1tb[i] = f2bu(eW1[((size_t)l * 257 + k) * 128 + n]);
        } else if (i < TB + TS) {
            int q = i - TB;
            int j = q & 7, r = q >> 3;
            int n = r & 127; r >>= 7;
            int ch = r & 3; r >>= 2;
            int sl = r & 3; int l = r >> 2;
            int k = sl * 32 + ch * 8 + j;
            w2tb[q] = f2bu(eW2[((size_t)l * 128 + k) * 128 + n]);
        } else if (i < TB + 2 * TS) {
            int q = i - TB - TS;
            int j = q & 7, r = q >> 3;
            int n = r & 127; r >>= 7;
            int ch = r & 3; r >>= 2;
            int sl = r & 3; int l = r >> 2;
            int k = sl * 32 + ch * 8 + j;
            c1tb[q] = f2bu(cW1[((size_t)l * 128 + k) * 128 + n]);
        } else if (i < 2 * TB + 2 * TS) {
            int q = i - TB - 2 * TS;
            int j = q & 7, r = q >> 3;
            int n = r & 127; r >>= 7;
            int ch = r & 3; r >>= 2;
            int sl = r & 7; int l = r >> 3;
            int k = sl * 32 + ch * 8 + j;
            n1tb[q] = f2bu(nW1[((size_t)l * 256 + k) * 128 + n]);
        } else if (i < 2 * TB + 3 * TS) {
            int q = i - 2 * TB - 2 * TS;
            int j = q & 7, r = q >> 3;
            int n = r & 127; r >>= 7;
            int ch = r & 3; r >>= 2;
            int sl = r & 3; int l = r >> 2;
            int k = sl * 32 + ch * 8 + j;
            n2tb[q] = f2bu(nW2[((size_t)l * 128 + k) * 128 + n]);
        } else {
            int r = i - 2 * TB - 3 * TS, l = r / 128, n = r % 128;
            w1d[r] = eW1[((size_t)l * 257 + 256) * 128 + n];
        }
    }
}

// ---------------------------------------------------------------- injection MLP (bf16 h out)
__global__ __launch_bounds__(256) void inj_kernel(
    const float* __restrict__ atom, const float* __restrict__ z,
    const float* __restrict__ W1, const float* __restrict__ b1,
    const float* __restrict__ W2, const float* __restrict__ b2,
    const float* __restrict__ W3, const float* __restrict__ b3,
    unsigned short* __restrict__ hb)
{
    __shared__ __align__(16) float in_s[16][84];
    __shared__ __align__(16) float s1[16][260];
    __shared__ __align__(16) float s2[16][132];
    const int tid = threadIdx.x;
    const int n0 = blockIdx.x * 16;

    if (tid < 80) {
        for (int e = 0; e < 16; ++e) {
            int n = n0 + e;
            in_s[e][tid] = (tid < 16) ? atom[n * 16 + tid] : z[(n >> 5) * 64 + (tid - 16)];
        }
    }
    __syncthreads();
    {
        float acc[16];
        float bias = b1[tid];
#pragma unroll
        for (int e = 0; e < 16; ++e) acc[e] = bias;
        for (int k4 = 0; k4 < 20; ++k4) {
            float w0 = W1[(k4 * 4 + 0) * 256 + tid];
            float w1 = W1[(k4 * 4 + 1) * 256 + tid];
            float w2 = W1[(k4 * 4 + 2) * 256 + tid];
            float w3 = W1[(k4 * 4 + 3) * 256 + tid];
#pragma unroll
            for (int e = 0; e < 16; ++e) {
                const float4 v = *(const float4*)&in_s[e][k4 * 4];
                acc[e] += v.x * w0 + v.y * w1 + v.z * w2 + v.w * w3;
            }
        }
#pragma unroll
        for (int e = 0; e < 16; ++e) s1[e][tid] = silu_f(acc[e]);
    }
    __syncthreads();
    const int j = tid & 127, hv = tid >> 7;
    {
        float acc[8];
        float bias = b2[j];
#pragma unroll
        for (int e = 0; e < 8; ++e) acc[e] = bias;
        for (int k4 = 0; k4 < 64; ++k4) {
            float w0 = W2[(k4 * 4 + 0) * 128 + j];
            float w1 = W2[(k4 * 4 + 1) * 128 + j];
            float w2 = W2[(k4 * 4 + 2) * 128 + j];
            float w3 = W2[(k4 * 4 + 3) * 128 + j];
#pragma unroll
            for (int e = 0; e < 8; ++e) {
                const float4 v = *(const float4*)&s1[hv * 8 + e][k4 * 4];
                acc[e] += v.x * w0 + v.y * w1 + v.z * w2 + v.w * w3;
            }
        }
#pragma unroll
        for (int e = 0; e < 8; ++e) s2[hv * 8 + e][j] = silu_f(acc[e]);
    }
    __syncthreads();
    {
        float acc[8];
        float bias = b3[j];
#pragma unroll
        for (int e = 0; e < 8; ++e) acc[e] = bias;
        for (int k4 = 0; k4 < 32; ++k4) {
            float w0 = W3[(k4 * 4 + 0) * 128 + j];
            float w1 = W3[(k4 * 4 + 1) * 128 + j];
            float w2 = W3[(k4 * 4 + 2) * 128 + j];
            float w3 = W3[(k4 * 4 + 3) * 128 + j];
#pragma unroll
            for (int e = 0; e < 8; ++e) {
                const float4 v = *(const float4*)&s2[hv * 8 + e][k4 * 4];
                acc[e] += v.x * w0 + v.y * w1 + v.z * w2 + v.w * w3;
            }
        }
#pragma unroll
        for (int e = 0; e < 8; ++e)
            hb[(size_t)(n0 + hv * 8 + e) * HDIM + j] = f2bu(acc[e]);
    }
}

// ---------------------------------------------------------------- MFMA edge kernel
// R12 structure (best known): 128 sorted edges x 128 ch, 4 waves, single-
// buffered 8KB slice staging, meta in Cbuf pad cols (dsq/cw f32 @128, row
// @130, col @131, dp bf16 @132..134). LDS 43008 B. Segmented scatters.
// MFMA layouts (HW-verified 16x16x32 bf16): A[m=l16][k=quad*8+j],
// B[k=quad*8+j][n=l16], D[m=quad*4+r][n=l16].
__global__ __launch_bounds__(256, 3) void edge_mfma_kernel(
    const unsigned short* __restrict__ hb, const float* __restrict__ pos,
    const int* __restrict__ rowS, const int* __restrict__ colS,
    const unsigned short* __restrict__ w1tb,   // [8 slice][4096]
    const unsigned short* __restrict__ w2tb,   // [4 slice][4096]
    const unsigned short* __restrict__ c1tb,   // [4 slice][4096]
    const float* __restrict__ w1d,
    const float* __restrict__ eb1, const float* __restrict__ eb2,
    const float* __restrict__ cb1, const float* __restrict__ cw2,
    float* __restrict__ agg, float* __restrict__ cu)
{
    __shared__ __align__(16) unsigned short Cbuf[128][136];  // h1/m + meta pad
    __shared__ __align__(16) unsigned short Bbuf[4096];      // one staged slice

    const int tid = threadIdx.x;
    const int e0 = blockIdx.x * 128;
    const int L = tid & 63, w = tid >> 6;
    const int quad = L >> 4, l16 = L & 15;
    const int m0 = w * 32;

    stage_slice(w1tb, Bbuf, w);   // slice 0 in flight during setup

    if (tid < 128) {
        int r = rowS[e0 + tid], c = colS[e0 + tid];
        float dx = pos[r * 3 + 0] - pos[c * 3 + 0];
        float dy = pos[r * 3 + 1] - pos[c * 3 + 1];
        float dz = pos[r * 3 + 2] - pos[c * 3 + 2];
        *(float*)&Cbuf[tid][128] = dx * dx + dy * dy + dz * dz;  // dsq
        Cbuf[tid][130] = (unsigned short)r;
        Cbuf[tid][131] = (unsigned short)c;
        Cbuf[tid][132] = f2bu(dx); Cbuf[tid][133] = f2bu(dy); Cbuf[tid][134] = f2bu(dz);
    }
    __syncthreads();   // setup + slice0 staged

    const int r0 = Cbuf[m0 + l16][130];
    const int r1 = Cbuf[m0 + 16 + l16][130];
    const int c0 = Cbuf[m0 + l16][131];
    const int c1 = Cbuf[m0 + 16 + l16][131];

    f32x4 acc[2][8];
    const f32x4 zero = {0.f, 0.f, 0.f, 0.f};

    // ---------- GEMM1: ef[128 x 256] @ W1, 8 k-slices (single-buffered)
#pragma unroll
    for (int mt = 0; mt < 2; ++mt)
#pragma unroll
        for (int nt = 0; nt < 8; ++nt) acc[mt][nt] = zero;

#pragma unroll
    for (int kc = 0; kc < 8; ++kc) {
        const int kk = (kc & 3) * 32 + quad * 8;
        const int n0i = (kc < 4) ? r0 : c0;
        const int n1i = (kc < 4) ? r1 : c1;
        bf16x8 a0 = *(const bf16x8*)(hb + (size_t)n0i * HDIM + kk);
        bf16x8 a1 = *(const bf16x8*)(hb + (size_t)n1i * HDIM + kk);
        const unsigned short* bp = Bbuf + quad * 1024;
#pragma unroll
        for (int nt = 0; nt < 8; ++nt) {
            bf16x8 b = *(const bf16x8*)&bp[(nt * 16 + l16) * 8];
            acc[0][nt] = __builtin_amdgcn_mfma_f32_16x16x32_bf16(a0, b, acc[0][nt], 0, 0, 0);
            acc[1][nt] = __builtin_amdgcn_mfma_f32_16x16x32_bf16(a1, b, acc[1][nt], 0, 0, 0);
        }
        __syncthreads();   // all reads of this slice done
        stage_slice((kc < 7) ? w1tb + (kc + 1) * 4096 : w2tb, Bbuf, w);
        if (kc == 7) {
            // epilogue1 overlaps w2-slice0 staging: + bias + dsq*wd, silu
#pragma unroll
            for (int nt = 0; nt < 8; ++nt) {
                const int n = nt * 16 + l16;
                const float wd = w1d[n];
                const float bias = eb1[n];
#pragma unroll
                for (int mt = 0; mt < 2; ++mt)
#pragma unroll
                    for (int r = 0; r < 4; ++r) {
                        const int m = m0 + mt * 16 + quad * 4 + r;
                        float dsq = *(const float*)&Cbuf[m][128];
                        Cbuf[m][n] = f2bu(silu_f(acc[mt][nt][r] + bias + dsq * wd));
                    }
            }
        }
        __syncthreads();   // next slice staged
    }

    // ---------- GEMM2: h1 @ W2 -> m (A = own-wave Cbuf rows, in-order DS)
#pragma unroll
    for (int mt = 0; mt < 2; ++mt)
#pragma unroll
        for (int nt = 0; nt < 8; ++nt) acc[mt][nt] = zero;
#pragma unroll
    for (int kc = 0; kc < 4; ++kc) {
        const int kk = kc * 32 + quad * 8;
        bf16x8 a0 = *(const bf16x8*)&Cbuf[m0 + l16][kk];
        bf16x8 a1 = *(const bf16x8*)&Cbuf[m0 + 16 + l16][kk];
        const unsigned short* bp = Bbuf + quad * 1024;
#pragma unroll
        for (int nt = 0; nt < 8; ++nt) {
            bf16x8 b = *(const bf16x8*)&bp[(nt * 16 + l16) * 8];
            acc[0][nt] = __builtin_amdgcn_mfma_f32_16x16x32_bf16(a0, b, acc[0][nt], 0, 0, 0);
            acc[1][nt] = __builtin_amdgcn_mfma_f32_16x16x32_bf16(a1, b, acc[1][nt], 0, 0, 0);
        }
        __syncthreads();
        stage_slice((kc < 3) ? w2tb + (kc + 1) * 4096 : c1tb, Bbuf, w);
        if (kc == 3) {
            // epilogue2: m = silu(acc + eb2) -> own rows
#pragma unroll
            for (int nt = 0; nt < 8; ++nt) {
                const int n = nt * 16 + l16;
                const float bias = eb2[n];
#pragma unroll
                for (int mt = 0; mt < 2; ++mt)
#pragma unroll
                    for (int r = 0; r < 4; ++r) {
                        const int m = m0 + mt * 16 + quad * 4 + r;
                        Cbuf[m][n] = f2bu(silu_f(acc[mt][nt][r] + bias));
                    }
            }
        }
        __syncthreads();
    }

    // ---------- GEMM3: m @ cW1 ; cw = silu(c1+cb1) . cW2
#pragma unroll
    for (int mt = 0; mt < 2; ++mt)
#pragma unroll
        for (int nt = 0; nt < 8; ++nt) acc[mt][nt] = zero;
#pragma unroll
    for (int kc = 0; kc < 4; ++kc) {
        const int kk = kc * 32 + quad * 8;
        bf16x8 a0 = *(const bf16x8*)&Cbuf[m0 + l16][kk];
        bf16x8 a1 = *(const bf16x8*)&Cbuf[m0 + 16 + l16][kk];
        const unsigned short* bp = Bbuf + quad * 1024;
#pragma unroll
        for (int nt = 0; nt < 8; ++nt) {
            bf16x8 b = *(const bf16x8*)&bp[(nt * 16 + l16) * 8];
            acc[0][nt] = __builtin_amdgcn_mfma_f32_16x16x32_bf16(a0, b, acc[0][nt], 0, 0, 0);
            acc[1][nt] = __builtin_amdgcn_mfma_f32_16x16x32_bf16(a1, b, acc[1][nt], 0, 0, 0);
        }
        if (kc < 3) {
            __syncthreads();
            stage_slice(c1tb + (kc + 1) * 4096, Bbuf, w);
            __syncthreads();
        }
    }
    {
        float s[2][4] = {{0.f, 0.f, 0.f, 0.f}, {0.f, 0.f, 0.f, 0.f}};
#pragma unroll
        for (int nt = 0; nt < 8; ++nt) {
            const int n = nt * 16 + l16;
            const float bias = cb1[n];
            const float wv = cw2[n];
#pragma unroll
            for (int mt = 0; mt < 2; ++mt)
#pragma unroll
                for (int r = 0; r < 4; ++r)
                    s[mt][r] += silu_f(acc[mt][nt][r] + bias) * wv;
        }
#pragma unroll
        for (int mt = 0; mt < 2; ++mt)
#pragma unroll
            for (int r = 0; r < 4; ++r) {
                float v = s[mt][r];
                v += __shfl_xor(v, 1);
                v += __shfl_xor(v, 2);
                v += __shfl_xor(v, 4);
                v += __shfl_xor(v, 8);
                if (l16 == 0)
                    *(float*)&Cbuf[m0 + mt * 16 + quad * 4 + r][128] = v;  // cw
            }
    }
    __syncthreads();   // m + cw visible to all waves

    // ---------- coord scatter: segmented over sorted rows (3 lanes)
    if (tid < 3) {
        int curr = Cbuf[0][130];
        float s = 0.0f;
        for (int e = 0; e < 128; ++e) {
            int r = Cbuf[e][130];
            if (r != curr) { atomicAdd(&cu[curr * 3 + tid], s); s = 0.0f; curr = r; }
            s += *(const float*)&Cbuf[e][128] * bu2f(Cbuf[e][132 + tid]);
        }
        atomicAdd(&cu[curr * 3 + tid], s);
    }
    // ---------- agg scatter: paired-channel segmented run-accumulate
    // wave q handles edges [q*32, q*32+32); lane p handles channels 2p, 2p+1.
    {
        const int q = tid >> 6;
        const int p = tid & 63;
        const int eb = q * 32;
        int curr = Cbuf[eb][130];
        float s0 = 0.0f, s1 = 0.0f;
#pragma unroll 4
        for (int i = 0; i < 32; ++i) {
            const int e = eb + i;
            int r = Cbuf[e][130];
            if (r != curr) {
                atomicAdd(&agg[(size_t)curr * HDIM + 2 * p], s0);
                atomicAdd(&agg[(size_t)curr * HDIM + 2 * p + 1], s1);
                s0 = 0.0f; s1 = 0.0f; curr = r;
            }
            unsigned int v = *(const unsigned int*)&Cbuf[e][2 * p];
            s0 += bu2f((unsigned short)(v & 0xffffu));
            s1 += bu2f((unsigned short)(v >> 16));
        }
        atomicAdd(&agg[(size_t)curr * HDIM + 2 * p], s0);
        atomicAdd(&agg[(size_t)curr * HDIM + 2 * p + 1], s1);
    }
}

// ---------------------------------------------------------------- MFMA node kernel
// 32 nodes x 128 ch per block, 2 waves, 128 threads, grid 256. Zero barriers.
// Zeroes agg/cu after consuming them (replaces per-layer memsets).
__global__ __launch_bounds__(128) void node_mfma_kernel(
    const unsigned short* __restrict__ hb,
    float* __restrict__ agg,
    float* __restrict__ cu, const float* __restrict__ deg,
    const unsigned short* __restrict__ n1tb,   // [8 slice][4096]
    const unsigned short* __restrict__ n2tb,   // [4 slice][4096]
    const float* __restrict__ b1, const float* __restrict__ b2,
    const float* __restrict__ lg, const float* __restrict__ lb,
    unsigned short* __restrict__ h2b,
    float* __restrict__ pos)
{
    __shared__ __align__(16) unsigned short Cbuf[32][136];
    const int tid = threadIdx.x;
    const int n0 = blockIdx.x * 32;

    if (tid < 32) {
        int n = n0 + tid;
        float inv = __builtin_amdgcn_rcpf(deg[n] + 1e-6f);
        pos[n * 3 + 0] += cu[n * 3 + 0] * inv;
        pos[n * 3 + 1] += cu[n * 3 + 1] * inv;
        pos[n * 3 + 2] += cu[n * 3 + 2] * inv;
        cu[n * 3 + 0] = 0.0f;
        cu[n * 3 + 1] = 0.0f;
        cu[n * 3 + 2] = 0.0f;
    }

    const int L = tid & 63, w = tid >> 6;     // w in {0,1}
    const int quad = L >> 4, l16 = L & 15;
    const int m0 = w * 16;
    const int row = n0 + m0 + l16;

    f32x4 acc[8];
    const f32x4 zero = {0.f, 0.f, 0.f, 0.f};

    // ---------- GEMM1: [h | agg] @ nW1
#pragma unroll
    for (int nt = 0; nt < 8; ++nt) acc[nt] = zero;
#pragma unroll
    for (int kc = 0; kc < 8; ++kc) {
        bf16x8 a;
        if (kc < 4) {
            const int kk = kc * 32 + quad * 8;
            a = *(const bf16x8*)(hb + (size_t)row * HDIM + kk);
        } else {
            const int kk = (kc - 4) * 32 + quad * 8;
            const float4* p = (const float4*)(agg + (size_t)row * HDIM + kk);
            float4 u0 = p[0], u1 = p[1];
            a[0] = (short)f2bu(u0.x); a[1] = (short)f2bu(u0.y);
            a[2] = (short)f2bu(u0.z); a[3] = (short)f2bu(u0.w);
            a[4] = (short)f2bu(u1.x); a[5] = (short)f2bu(u1.y);
            a[6] = (short)f2bu(u1.z); a[7] = (short)f2bu(u1.w);
        }
        const unsigned short* bp = n1tb + ((kc * 4 + quad) * 128) * 8;
#pragma unroll
        for (int nt = 0; nt < 8; ++nt) {
            bf16x8 b = *(const bf16x8*)(bp + (nt * 16 + l16) * 8);
            acc[nt] = __builtin_amdgcn_mfma_f32_16x16x32_bf16(a, b, acc[nt], 0, 0, 0);
        }
    }
    // zero own agg rows (already consumed)
    {
        const float4 z4 = {0.f, 0.f, 0.f, 0.f};
        float4* ap = (float4*)(agg + (size_t)row * HDIM + quad * 32);
#pragma unroll
        for (int i = 0; i < 8; ++i) ap[i] = z4;
    }
#pragma unroll
    for (int nt = 0; nt < 8; ++nt) {
        const int n = nt * 16 + l16;
        const float bias = b1[n];
#pragma unroll
        for (int r = 0; r < 4; ++r) {
            const int m = m0 + quad * 4 + r;
            Cbuf[m][n] = f2bu(silu_f(acc[nt][r] + bias));
        }
    }

    // ---------- GEMM2: s1 @ nW2 -> nu
#pragma unroll
    for (int nt = 0; nt < 8; ++nt) acc[nt] = zero;
#pragma unroll
    for (int kc = 0; kc < 4; ++kc) {
        const int kk = kc * 32 + quad * 8;
        bf16x8 a = *(const bf16x8*)&Cbuf[m0 + l16][kk];
        const unsigned short* bp = n2tb + ((kc * 4 + quad) * 128) * 8;
#pragma unroll
        for (int nt = 0; nt < 8; ++nt) {
            bf16x8 b = *(const bf16x8*)(bp + (nt * 16 + l16) * 8);
            acc[nt] = __builtin_amdgcn_mfma_f32_16x16x32_bf16(a, b, acc[nt], 0, 0, 0);
        }
    }

    // epilogue 2: x = h + nu + b2 ; LN via 16-lane shuffle ; write h2b
#pragma unroll
    for (int nt = 0; nt < 8; ++nt) {
        const int n = nt * 16 + l16;
        const float bias = b2[n];
#pragma unroll
        for (int r = 0; r < 4; ++r) {
            const int m = m0 + quad * 4 + r;
            acc[nt][r] += bias + bu2f(hb[(size_t)(n0 + m) * HDIM + n]);
        }
    }
    float mu[4], rs[4];
#pragma unroll
    for (int r = 0; r < 4; ++r) {
        float s = 0.0f, ss = 0.0f;
#pragma unroll
        for (int nt = 0; nt < 8; ++nt) {
            float x = acc[nt][r];
            s += x; ss += x * x;
        }
#pragma unroll
        for (int d = 1; d < 16; d <<= 1) {
            s += __shfl_xor(s, d);
            ss += __shfl_xor(ss, d);
        }
        float m_ = s * (1.0f / 128.0f);
        float var = ss * (1.0f / 128.0f) - m_ * m_;
        mu[r] = m_;
        rs[r] = rsqrtf(fmaxf(var, 0.0f) + 1e-5f);
    }
#pragma unroll
    for (int nt = 0; nt < 8; ++nt) {
        const int n = nt * 16 + l16;
        const float gg = lg[n], bb = lb[n];
#pragma unroll
        for (int r = 0; r < 4; ++r) {
            const int m = m0 + quad * 4 + r;
            float val = (acc[nt][r] - mu[r]) * rs[r] * gg + bb;
            h2b[(size_t)(n0 + m) * HDIM + n] = f2bu(val);
        }
    }
}

// ---------------------------------------------------------------- launch
extern "C" void kernel_launch(void* const* d_in, const int* in_sizes, int n_in,
                              void* d_out, int out_size, void* d_ws, size_t ws_size,
                              hipStream_t stream) {
    const float* zF    = (const float*)d_in[0];
    const float* atomF = (const float*)d_in[1];
    const float* posI  = (const float*)d_in[2];
    const void*  ei    = d_in[3];
    const float* iW1 = (const float*)d_in[5];  const float* ib1 = (const float*)d_in[6];
    const float* iW2 = (const float*)d_in[7];  const float* ib2 = (const float*)d_in[8];
    const float* iW3 = (const float*)d_in[9];  const float* ib3 = (const float*)d_in[10];
    const float* eW1 = (const float*)d_in[11]; const float* eb1 = (const float*)d_in[12];
    const float* eW2 = (const float*)d_in[13]; const float* eb2 = (const float*)d_in[14];
    const float* nW1 = (const float*)d_in[15]; const float* nb1 = (const float*)d_in[16];
    const float* nW2 = (const float*)d_in[17]; const float* nb2 = (const float*)d_in[18];
    const float* cW1 = (const float*)d_in[19]; const float* cb1 = (const float*)d_in[20];
    const float* cW2 = (const float*)d_in[21];
    const float* lng = (const float*)d_in[22]; const float* lnb = (const float*)d_in[23];

    float* pos = (float*)d_out;   // fp32 output (verified R5)

    float* ws = (float*)d_ws;
    int* flags = (int*)d_ws;
    size_t cur = 16;
    auto carve = [&](size_t n) { float* p = ws + cur; cur += n; return p; };
    float* deg  = carve(NNODES);
    float* cu   = carve((size_t)NNODES * 3);
    float* agg  = carve((size_t)NNODES * HDIM);
    unsigned short* hbA = (unsigned short*)carve((size_t)NNODES * HDIM / 2);
    unsigned short* hbB = (unsigned short*)carve((size_t)NNODES * HDIM / 2);
    unsigned short* w1tb = (unsigned short*)carve((size_t)NLAYERS * 8 * 4096 / 2);
    unsigned short* w2tb = (unsigned short*)carve((size_t)NLAYERS * 4 * 4096 / 2);
    unsigned short* c1tb = (unsigned short*)carve((size_t)NLAYERS * 4 * 4096 / 2);
    unsigned short* n1tb = (unsigned short*)carve((size_t)NLAYERS * 8 * 4096 / 2);
    unsigned short* n2tb = (unsigned short*)carve((size_t)NLAYERS * 4 * 4096 / 2);
    float* w1d  = carve(NLAYERS * 128);
    int* cnt    = (int*)carve(NNODES);
    int* woff   = (int*)carve(NNODES);
    int* rowS   = (int*)carve(NEDGES);
    int* colS   = (int*)carve(NEDGES);

    detect_kernel<<<1, 64, 0, stream>>>((const int*)ei, flags);
    pos_init_kernel<<<(NNODES * 3 + 255) / 256, 256, 0, stream>>>(posI, pos);

    hipMemsetAsync(cnt, 0, NNODES * sizeof(int), stream);
    cnt_kernel<<<NEDGES / 256, 256, 0, stream>>>(ei, flags, cnt);
    scan_kernel<<<1, 256, 0, stream>>>(cnt, woff, deg);
    scatter_kernel<<<NEDGES / 256, 256, 0, stream>>>(ei, flags, woff, rowS, colS);

    prep_weights_kernel<<<2691, 256, 0, stream>>>(eW1, eW2, cW1, nW1, nW2,
                                                  w1tb, w2tb, c1tb, n1tb, n2tb, w1d);
    inj_kernel<<<NNODES / 16, 256, 0, stream>>>(atomF, zF, iW1, ib1, iW2, ib2, iW3, ib3,
                                                hbA);

    // layer-0 zeroing only; node_mfma_kernel zeroes agg/cu for later layers
    hipMemsetAsync(agg, 0, (size_t)NNODES * HDIM * sizeof(float), stream);
    hipMemsetAsync(cu, 0, (size_t)NNODES * 3 * sizeof(float), stream);

    unsigned short* hb = hbA;
    unsigned short* ob = hbB;
    for (int l = 0; l < NLAYERS; ++l) {
        edge_mfma_kernel<<<NEDGES / 128, 256, 0, stream>>>(
            hb, pos, rowS, colS,
            w1tb + (size_t)l * 8 * 4096,
            w2tb + (size_t)l * 4 * 4096,
            c1tb + (size_t)l * 4 * 4096,
            w1d + (size_t)l * 128,
            eb1 + l * 128, eb2 + l * 128, cb1 + l * 128, cW2 + l * 128,
            agg, cu);
        node_mfma_kernel<<<NNODES / 32, 128, 0, stream>>>(
            hb, agg, cu, deg,
            n1tb + (size_t)l * 8 * 4096,
            n2tb + (size_t)l * 4 * 4096,
            nb1 + l * 128, nb2 + l * 128,
            lng + l * 128, lnb + l * 128,
            /*h2b=*/ob, pos);
        unsigned short* tb = hb; hb = ob; ob = tb;
    }
}